// Round 7
// baseline (316.641 us; speedup 1.0000x reference)
//
#include <hip/hip_runtime.h>
#include <math.h>

#define NX   160
#define N2   25600        // 160*160
#define N3   4096000      // 160^3
#define NB   4

#define ZSLAB 20          // z-planes owned per XCD (160/8)
#define NBLK_S 2048       // sums kernel: 512 blocks per batch
#define SBLK_PER_B 512
#define F4_PER_BLK 2000   // 1024000 float4 per batch / 512 blocks
#define ZCH  20           // z-run per fused_conv thread (= one slab)
#define NBLK_Z 800        // 8 xcd * 100 units

// 1D Gaussian taps exp(-d^2/50), d=-4..4 (NOT normalized, matches reference)
__device__ __constant__ float G1[9] = {
    0.72614903f, 0.83527021f, 0.92311635f, 0.98019867f, 1.0f,
    0.98019867f, 0.92311635f, 0.83527021f, 0.72614903f};

// edge sums: FULL - missing taps at low/high boundary
#define ES_FULL 7.92946852f
__device__ __constant__ float ES_M[4] = {3.46473426f, 2.48453559f, 1.56141924f,
                                         0.72614903f};
__device__ inline float edge_sum(int i) {
    float s = ES_FULL;
    if (i < 4) s -= ES_M[i];
    if (i > NX - 5) s -= ES_M[NX - 1 - i];
    return s;
}

__device__ inline float4 f4_zero() { return make_float4(0.f, 0.f, 0.f, 0.f); }
__device__ inline float4 f4_axpy(float a, float4 b, float4 c) {
    return make_float4(c.x + a * b.x, c.y + a * b.y, c.z + a * b.z, c.w + a * b.w);
}

// R10: on-the-fly separable x+y conv of labels at (x0..x0+3, y) in plane.
// 9 rows x (12->4 x-conv) fused with the y-dot. Replaces the fp16 t-load.
__device__ inline float4 xyconv4(const float* __restrict__ plane, int x0, int y) {
    float4 acc = f4_zero();
#pragma unroll
    for (int dy = 0; dy < 9; ++dy) {
        int gy = y - 4 + dy;
        if (gy >= 0 && gy < NX) {
            const float* row = plane + gy * NX;
            float w[12];
#pragma unroll
            for (int c = 0; c < 3; ++c) {
                int gx = x0 - 4 + 4 * c;
                float4 v = (gx >= 0 && gx <= NX - 4) ? *(const float4*)&row[gx]
                                                     : f4_zero();
                w[4 * c] = v.x; w[4 * c + 1] = v.y;
                w[4 * c + 2] = v.z; w[4 * c + 3] = v.w;
            }
            float4 o = f4_zero();
#pragma unroll
            for (int k = 0; k < 9; ++k) {
                float g = G1[k];
                o.x += g * w[k];     o.y += g * w[k + 1];
                o.z += g * w[k + 2]; o.w += g * w[k + 3];
            }
            acc = f4_axpy(G1[dy], o, acc);
        }
    }
    return acc;
}

// block = 256 threads (4 waves). Reduce NV doubles, plain store.
template <int NV>
__device__ inline void block_reduce_store(double* vals, double* dst) {
    __shared__ double red[4][NV];
    int lane = threadIdx.x & 63;
    int wave = threadIdx.x >> 6;
#pragma unroll
    for (int v = 0; v < NV; ++v) {
        double x = vals[v];
#pragma unroll
        for (int off = 32; off > 0; off >>= 1) x += __shfl_down(x, off, 64);
        if (lane == 0) red[wave][v] = x;
    }
    __syncthreads();
    if (threadIdx.x < NV) {
        int v = threadIdx.x;
        dst[v] = red[0][v] + red[1][v] + red[2][v] + red[3][v];
    }
}

// R10: pure streaming per-batch sums (the only reason conv_xy existed once t
// is recomputed in the z-pass). Coalesced float4, grid-stride within chunk.
__global__ __launch_bounds__(256) void sums_kernel(
    const float* __restrict__ labels, const float* __restrict__ inputs,
    double* __restrict__ pS) {
    int blk = blockIdx.x;
    int b = blk >> 9;          // 0..3
    int chunk = blk & 511;
    const float4* lp = (const float4*)(labels + b * N3) + chunk * F4_PER_BLK;
    const float4* ip = (const float4*)(inputs + b * N3) + chunk * F4_PER_BLK;
    double sp = 0.0, sip = 0.0, si = 0.0;
    for (int i = threadIdx.x; i < F4_PER_BLK; i += 256) {
        float4 p = lp[i];
        float4 in = ip[i];
        sp += (double)(p.x + p.y + p.z + p.w);
        sip += (double)(in.x * p.x + in.y * p.y + in.z * p.z + in.w * p.w);
        si += (double)(in.x + in.y + in.z + in.w);
    }
    double vals[3] = {sp, sip, si};
    block_reduce_store<3>(vals, pS + 3 * blk);
}

// R10: fully-fused conv pass — z-conv register sliding window where win[9]
// holds ON-THE-FLY fp32 xy-conv values (t buffer eliminated entirely).
// Slab-mapped: xcd = bid&7 owns z in [20*xcd, 20*xcd+20); label z-halo reads
// stay in that XCD's L2. Fused S reduce: every block reduces its batch's
// pS[512b .. 512b+512) in identical order -> identical m0/m1 across blocks.
__global__ __launch_bounds__(256) void fused_conv_kernel(
    const float* __restrict__ labels, const float* __restrict__ inputs,
    const double* __restrict__ pS, double* __restrict__ pZ) {
    int tid = threadIdx.x;
    int xcd = blockIdx.x & 7;
    int c = blockIdx.x >> 3;      // 0..99
    int idx = c * 256 + tid;      // 0..25599 within XCD
    int x4 = idx % 40;            // float4 column; x = 4*x4
    int rest = idx / 40;          // 0..639
    int y = rest % NX;
    int b = rest / NX;            // uniform per block (6400 % 256 == 0)
    int z0 = ZSLAB * xcd;

    // ---- fused S reduce ----
    __shared__ float sM[2];
    {
        double v0 = 0, v1 = 0, v2 = 0;
        for (int i = tid; i < SBLK_PER_B; i += 256) {
            const double* p = pS + 3 * (SBLK_PER_B * b + i);
            v0 += p[0]; v1 += p[1]; v2 += p[2];
        }
        __shared__ double red[4][3];
        int lane = tid & 63, wave = tid >> 6;
        double vals[3] = {v0, v1, v2};
#pragma unroll
        for (int v = 0; v < 3; ++v) {
            double x = vals[v];
#pragma unroll
            for (int off = 32; off > 0; off >>= 1) x += __shfl_down(x, off, 64);
            if (lane == 0) red[wave][v] = x;
        }
        __syncthreads();
        if (tid == 0) {
            double sp = red[0][0] + red[1][0] + red[2][0] + red[3][0];
            double sip = red[0][1] + red[1][1] + red[2][1] + red[3][1];
            double si = red[0][2] + red[1][2] + red[2][2] + red[3][2];
            const double Nv = (double)N3;
            sM[0] = (float)((sip / Nv) / (sp / Nv + 1e-5));
            sM[1] = (float)(((si - sip) / Nv) / ((Nv - sp) / Nv + 1e-5));
        }
        __syncthreads();
    }
    float m0 = sM[0], m1 = sM[1];

    int x = x4 * 4;
    float ey = edge_sum(y);
    float cx[4] = {edge_sum(x) * ey, edge_sum(x + 1) * ey,
                   edge_sum(x + 2) * ey, edge_sum(x + 3) * ey};

    const float* lbase = labels + b * N3;
    const float* ibase = inputs + b * N3;
    int po = y * NX + x;          // in-plane offset for center loads

    // fill window: xy-conv at planes z0-4 .. z0+4
    float4 win[9];
#pragma unroll
    for (int d = 0; d < 9; ++d) {
        int z = z0 - 4 + d;
        win[d] = (z >= 0 && z < NX) ? xyconv4(lbase + z * N2, x, y) : f4_zero();
    }

    float n0 = 0.f, d0 = 0.f, n1 = 0.f, d1 = 0.f;
    for (int zz = 0; zz < ZCH; ++zz) {
        int z = z0 + zz;
        // next window plane: fresh xy-conv (long FMA chain hides own loads)
        int zl = z + 5;
        float4 tn = (zl < NX) ? xyconv4(lbase + zl * N2, x, y) : f4_zero();
        float4 pv = *(const float4*)&lbase[z * N2 + po];
        float4 iv = *(const float4*)&ibase[z * N2 + po];

        float4 c4 = f4_zero();
#pragma unroll
        for (int d = 0; d < 9; ++d) c4 = f4_axpy(G1[d], win[d], c4);
        float ez = edge_sum(z);
        float pc[4] = {pv.x, pv.y, pv.z, pv.w};
        float ic[4] = {iv.x, iv.y, iv.z, iv.w};
        float cc[4] = {c4.x, c4.y, c4.z, c4.w};
#pragma unroll
        for (int l = 0; l < 4; ++l) {
            float c1 = cx[l] * ez - cc[l];  // conv(1-p) via conv(ones)
            float df0 = ic[l] - m0; df0 *= df0;
            float w0 = __expf(-df0 * df0);
            float df1 = ic[l] - m1; df1 *= df1;
            float w1 = __expf(-df1 * df1);
            n0 += cc[l] * pc[l] * w0;
            d0 += cc[l] * w0;
            n1 += c1 * (1.f - pc[l]) * w1;
            d1 += c1 * w1;
        }
#pragma unroll
        for (int d = 0; d < 8; ++d) win[d] = win[d + 1];
        win[8] = tn;
    }
    double vals[4] = {(double)n0, (double)d0, (double)n1, (double)d1};
    block_reduce_store<4>(vals, pZ + 4 * blockIdx.x);
}

// single block: sum 800 per-block partials, compute final loss
__global__ __launch_bounds__(256) void finalize_kernel(
    const double* __restrict__ pZ, float* __restrict__ out) {
    double a0 = 0, a1 = 0, a2 = 0, a3 = 0;
    for (int i = threadIdx.x; i < NBLK_Z; i += 256) {
        const double* p = &pZ[4 * i];
        a0 += p[0]; a1 += p[1]; a2 += p[2]; a3 += p[3];
    }
    __shared__ double red[4][4];
    int lane = threadIdx.x & 63;
    int wave = threadIdx.x >> 6;
    double vals[4] = {a0, a1, a2, a3};
#pragma unroll
    for (int v = 0; v < 4; ++v) {
        double x = vals[v];
#pragma unroll
        for (int off = 32; off > 0; off >>= 1) x += __shfl_down(x, off, 64);
        if (lane == 0) red[wave][v] = x;
    }
    __syncthreads();
    if (threadIdx.x == 0) {
        double acc[4];
#pragma unroll
        for (int v = 0; v < 4; ++v)
            acc[v] = red[0][v] + red[1][v] + red[2][v] + red[3][v];
        double r0 = fabs(acc[0] / (acc[1] + 1e-6));
        double r1 = fabs(acc[2] / (acc[3] + 1e-6));
        out[0] = (float)(2.0 - r0 - r1);
    }
}

extern "C" void kernel_launch(void* const* d_in, const int* in_sizes, int n_in,
                              void* d_out, int out_size, void* d_ws, size_t ws_size,
                              hipStream_t stream) {
    const float* labels = (const float*)d_in[0];
    const float* inputs = (const float*)d_in[1];
    float* out = (float*)d_out;

    // ws layout:
    //   [0)       pS : 2048*3 doubles = 49152 B
    //   [192128)  pZ : 800*4 doubles = 25600 B  (ends 217728)
    //   (t buffer eliminated)
    double* pS = (double*)d_ws;
    double* pZ = (double*)((char*)d_ws + 192128);

    hipLaunchKernelGGL(sums_kernel, dim3(NBLK_S), dim3(256), 0, stream,
                       labels, inputs, pS);
    hipLaunchKernelGGL(fused_conv_kernel, dim3(NBLK_Z), dim3(256), 0, stream,
                       labels, inputs, pS, pZ);
    hipLaunchKernelGGL(finalize_kernel, dim3(1), dim3(256), 0, stream, pZ, out);
}